// Round 1
// baseline (1193.289 us; speedup 1.0000x reference)
//
#include <hip/hip_runtime.h>
#include <cstdint>

#define HH 480
#define WW 640
#define BATCH 8
#define NPIX (HH * WW)
#define TOPK 500
#define NBINS 4096
#define CAP 1024

// ---------------------------------------------------------------------------
// 5x5 max pool with -inf border (reduce_window semantics). If supp != nullptr,
// the pooled input is (supp[p] > 0 ? 0 : in[p])  (suppressed scores).
// Separable: rowmax into LDS, then colmax.
// ---------------------------------------------------------------------------
__global__ __launch_bounds__(256) void maxpool5_k(const float* __restrict__ in,
                                                  const float* __restrict__ supp,
                                                  float* __restrict__ out) {
    __shared__ float tile[12][36];
    __shared__ float rmax[12][32];
    int bx = blockIdx.x * 32, by = blockIdx.y * 8, b = blockIdx.z;
    const float* img = in + (size_t)b * NPIX;
    const float* sup = supp ? supp + (size_t)b * NPIX : nullptr;
    int tx = threadIdx.x, ty = threadIdx.y;
    int lin = ty * 32 + tx;
    for (int i = lin; i < 12 * 36; i += 256) {
        int r = i / 36, c = i - r * 36;
        int gy = by + r - 2, gx = bx + c - 2;
        float v = -INFINITY;
        if (gy >= 0 && gy < HH && gx >= 0 && gx < WW) {
            v = img[gy * WW + gx];
            if (sup && sup[gy * WW + gx] > 0.0f) v = 0.0f;
        }
        tile[r][c] = v;
    }
    __syncthreads();
    for (int i = lin; i < 12 * 32; i += 256) {
        int r = i >> 5, c = i & 31;
        float m = tile[r][c];
        m = fmaxf(m, tile[r][c + 1]);
        m = fmaxf(m, tile[r][c + 2]);
        m = fmaxf(m, tile[r][c + 3]);
        m = fmaxf(m, tile[r][c + 4]);
        rmax[r][c] = m;
    }
    __syncthreads();
    float m = rmax[ty][tx];
    m = fmaxf(m, rmax[ty + 1][tx]);
    m = fmaxf(m, rmax[ty + 2][tx]);
    m = fmaxf(m, rmax[ty + 3][tx]);
    m = fmaxf(m, rmax[ty + 4][tx]);
    out[(size_t)b * NPIX + (size_t)(by + ty) * WW + (bx + tx)] = m;
}

// mask = (scores == maxpool) ? 1 : 0
__global__ __launch_bounds__(256) void mask_init_k(const float* __restrict__ s,
                                                   const float* __restrict__ m0,
                                                   float* __restrict__ mask) {
    int g = blockIdx.x * 256 + threadIdx.x;
    if (g < BATCH * NPIX) mask[g] = (s[g] == m0[g]) ? 1.0f : 0.0f;
}

// mask |= (supp_scores == maxpool(supp_scores)) & ~supp_mask
// supp_mask = dil>0 ; supp_scores recomputed elementwise from dil+scores
__global__ __launch_bounds__(256) void mask_update_k(float* __restrict__ mask,
                                                     const float* __restrict__ dil,
                                                     const float* __restrict__ s,
                                                     const float* __restrict__ mss) {
    int g = blockIdx.x * 256 + threadIdx.x;
    if (g >= BATCH * NPIX) return;
    bool suppd = dil[g] > 0.0f;
    float ssv = suppd ? 0.0f : s[g];
    if (!suppd && (ssv == mss[g])) mask[g] = 1.0f;
}

__device__ __forceinline__ int bucket_of(float v) {
    int bk = (int)(v * 4096.0f);  // exact: *2^12 is monotone & exact for v in [0,1)
    return bk > 4095 ? 4095 : (bk < 0 ? 0 : bk);
}

// per-batch histogram of survivor values (mask & border-zeroing applied)
__global__ __launch_bounds__(256) void histo_k(const float* __restrict__ s,
                                               const float* __restrict__ mask,
                                               unsigned* __restrict__ hist) {
    int g = blockIdx.x * 256 + threadIdx.x;
    if (g >= BATCH * NPIX) return;
    int b = g / NPIX;
    int p = g - b * NPIX;
    int y = p / WW, x = p - y * WW;
    if (mask[g] > 0.0f && y >= 3 && y <= HH - 3 && x >= 3 && x <= WW - 3) {
        atomicAdd(&hist[b * NBINS + bucket_of(s[g])], 1u);
    }
}

// find smallest bucket B* with cum-count-from-top >= TOPK
__global__ __launch_bounds__(256) void scan_k(const unsigned* __restrict__ hist,
                                              int* __restrict__ bstar) {
    int b = blockIdx.x;
    __shared__ unsigned h[NBINS];
    for (int i = threadIdx.x; i < NBINS; i += 256) h[i] = hist[b * NBINS + i];
    __syncthreads();
    if (threadIdx.x == 0) {
        unsigned cum = 0;
        int B = 0;
        for (int bin = NBINS - 1; bin >= 0; --bin) {
            cum += h[bin];
            if (cum >= TOPK) { B = bin; break; }
        }
        bstar[b] = B;
    }
}

// compact candidates (bucket >= B*) into per-batch key arrays.
// key = (float_bits << 32) | (0xFFFFFFFF - pix): descending sort of keys gives
// value-descending, index-ascending (stable top_k tie-break).
__global__ __launch_bounds__(256) void compact_k(const float* __restrict__ s,
                                                 const float* __restrict__ mask,
                                                 const int* __restrict__ bstar,
                                                 unsigned* __restrict__ cnt,
                                                 unsigned long long* __restrict__ cand) {
    int g = blockIdx.x * 256 + threadIdx.x;
    if (g >= BATCH * NPIX) return;
    int b = g / NPIX;
    int p = g - b * NPIX;
    int y = p / WW, x = p - y * WW;
    if (mask[g] > 0.0f && y >= 3 && y <= HH - 3 && x >= 3 && x <= WW - 3) {
        float v = s[g];
        if (bucket_of(v) >= bstar[b]) {
            unsigned pos = atomicAdd(&cnt[b], 1u);
            if (pos < CAP) {
                unsigned long long key =
                    ((unsigned long long)__float_as_uint(v) << 32) |
                    (unsigned long long)(0xFFFFFFFFu - (unsigned)p);
                cand[(size_t)b * CAP + pos] = key;
            }
        }
    }
}

__device__ __forceinline__ unsigned long long shfl_xor_u64(unsigned long long v, int m) {
    int lo = __shfl_xor((int)(unsigned)(v & 0xFFFFFFFFull), m, 64);
    int hi = __shfl_xor((int)(unsigned)(v >> 32), m, 64);
    return ((unsigned long long)(unsigned)hi << 32) | (unsigned long long)(unsigned)lo;
}

// Per-batch: bitonic sort 1024 keys descending (1 elem/thread), take top-500,
// compute softmax refinement + kxy + kptscore + disp, then descriptor sampling.
__global__ __launch_bounds__(1024) void finalize_k(const float* __restrict__ sc,
                                                   const float* __restrict__ dm,
                                                   const unsigned* __restrict__ cnt,
                                                   const unsigned long long* __restrict__ cand,
                                                   float* __restrict__ out) {
    int b = blockIdx.x;
    int tid = threadIdx.x;
    __shared__ unsigned long long skeys[1024];
    __shared__ float spx[TOPK], spy[TOPK];

    unsigned n = cnt[b];
    if (n > CAP) n = CAP;
    unsigned long long key = (tid < (int)n) ? cand[(size_t)b * CAP + tid] : 0ULL;

    // bitonic sort, overall DESCENDING; element index == tid
    for (unsigned kk = 2; kk <= 1024; kk <<= 1) {
        for (unsigned j = kk >> 1; j > 0; j >>= 1) {
            unsigned long long partner;
            if (j >= 64) {
                __syncthreads();
                skeys[tid] = key;
                __syncthreads();
                partner = skeys[tid ^ j];
            } else {
                partner = shfl_xor_u64(key, (int)j);
            }
            bool inDesc = ((tid & kk) == 0);
            bool iLower = ((tid & j) == 0);
            bool keepMax = (inDesc == iLower);
            unsigned long long mx = key > partner ? key : partner;
            unsigned long long mn = key > partner ? partner : key;
            key = keepMax ? mx : mn;
        }
    }
    __syncthreads();

    // ---- phase 1: per-keypoint softmax refinement (thread k = keypoint k)
    if (tid < TOPK) {
        unsigned lo = (unsigned)(key & 0xFFFFFFFFull);
        int pix = (key == 0ULL) ? 0 : (int)(0xFFFFFFFFu - lo);
        int ys = pix / WW, xs = pix - ys * WW;
        const float* sp = sc + (size_t)b * NPIX;

        float p[25];
        float mxv = -INFINITY;
#pragma unroll
        for (int dy = 0; dy < 5; ++dy) {
            int iy = ys + dy - 2;
            iy = iy < 0 ? 0 : (iy > HH - 1 ? HH - 1 : iy);
#pragma unroll
            for (int dx = 0; dx < 5; ++dx) {
                int ix = xs + dx - 2;
                ix = ix < 0 ? 0 : (ix > WW - 1 ? WW - 1 : ix);
                float v = sp[iy * WW + ix];
                p[dy * 5 + dx] = v;
                mxv = fmaxf(mxv, v);
            }
        }
        float se = 0.f, sx = 0.f, sy = 0.f;
#pragma unroll
        for (int i = 0; i < 25; ++i) {
            float e = expf((p[i] - mxv) * 10.0f);  // 1/T, T=0.1
            p[i] = e;
            se += e;
            sx += e * (float)((i % 5) - 2);
            sy += e * (float)((i / 5) - 2);
        }
        float invs = 1.0f / (se + 1e-12f);
        float xr = sx * invs, yr = sy * invs;
        float dnum = 0.f;
#pragma unroll
        for (int i = 0; i < 25; ++i) {
            float ddx = ((float)((i % 5) - 2) - xr) * 0.5f;
            float ddy = ((float)((i / 5) - 2) - yr) * 0.5f;
            dnum += p[i] * (ddx * ddx + ddy * ddy);
        }
        float disp = dnum * invs;

        float kxn = ((float)xs + xr) / 639.0f * 2.0f - 1.0f;
        float kyn = ((float)ys + yr) / 479.0f * 2.0f - 1.0f;
        out[((size_t)b * TOPK + tid) * 2 + 0] = kxn;
        out[((size_t)b * TOPK + tid) * 2 + 1] = kyn;

        float px = fminf(fmaxf((kxn + 1.0f) * 0.5f * 639.0f, 0.0f), 639.0f);
        float py = fminf(fmaxf((kyn + 1.0f) * 0.5f * 479.0f, 0.0f), 479.0f);
        int x0 = (int)floorf(px), y0 = (int)floorf(py);
        int x1 = x0 + 1 > WW - 1 ? WW - 1 : x0 + 1;
        int y1 = y0 + 1 > HH - 1 ? HH - 1 : y0 + 1;
        float wx = px - (float)x0, wy = py - (float)y0;
        float v00 = sp[y0 * WW + x0], v01 = sp[y0 * WW + x1];
        float v10 = sp[y1 * WW + x0], v11 = sp[y1 * WW + x1];
        float ks = v00 * (1 - wx) * (1 - wy) + v01 * wx * (1 - wy) +
                   v10 * (1 - wx) * wy + v11 * wx * wy;
        out[264000 + b * TOPK + tid] = ks;
        out[268000 + b * TOPK + tid] = disp;
        spx[tid] = px;
        spy[tid] = py;
    }
    __syncthreads();

    // ---- phase 2: descriptor sampling; wave per keypoint, lane = channel
    int wave = tid >> 6, lane = tid & 63;
    for (int kp = wave; kp < TOPK; kp += 16) {
        float px = spx[kp], py = spy[kp];
        int x0 = (int)floorf(px), y0 = (int)floorf(py);
        int x1 = x0 + 1 > WW - 1 ? WW - 1 : x0 + 1;
        int y1 = y0 + 1 > HH - 1 ? HH - 1 : y0 + 1;
        float wx = px - (float)x0, wy = py - (float)y0;
        const float* ch = dm + ((size_t)b * 64 + lane) * NPIX;
        float v00 = ch[y0 * WW + x0], v01 = ch[y0 * WW + x1];
        float v10 = ch[y1 * WW + x0], v11 = ch[y1 * WW + x1];
        float d = v00 * (1 - wx) * (1 - wy) + v01 * wx * (1 - wy) +
                  v10 * (1 - wx) * wy + v11 * wx * wy;
        float ssq = d * d;
#pragma unroll
        for (int m = 32; m; m >>= 1) ssq += __shfl_xor(ssq, m, 64);
        float inv = 1.0f / fmaxf(sqrtf(ssq), 1e-12f);
        out[8000 + ((size_t)b * TOPK + kp) * 64 + lane] = d * inv;
    }
}

extern "C" void kernel_launch(void* const* d_in, const int* in_sizes, int n_in,
                              void* d_out, int out_size, void* d_ws, size_t ws_size,
                              hipStream_t stream) {
    const float* sc = (const float*)d_in[0];
    const float* dm = (const float*)d_in[1];
    float* out = (float*)d_out;

    char* ws = (char*)d_ws;
    const size_t NP = (size_t)BATCH * NPIX * sizeof(float);  // 9,830,400 B
    float* t1 = (float*)(ws);
    float* t2 = (float*)(ws + NP);
    float* maskb = (float*)(ws + 2 * NP);
    unsigned* hist = (unsigned*)(ws + 3 * NP);
    unsigned* cnt = hist + (size_t)BATCH * NBINS;
    int* bstar = (int*)(cnt + BATCH);
    unsigned long long* cand =
        (unsigned long long*)(ws + 3 * NP + ((size_t)BATCH * NBINS + 2 * BATCH) * 4 + 32);

    // zero hist + cnt (contiguous)
    hipMemsetAsync(hist, 0, ((size_t)BATCH * NBINS + BATCH) * sizeof(unsigned), stream);

    dim3 mpG(20, 60, 8), mpB(32, 8);
    const int EW_G = (BATCH * NPIX) / 256;  // 9600 exact

    // max_mask = scores == maxpool(scores)
    maxpool5_k<<<mpG, mpB, 0, stream>>>(sc, nullptr, t1);
    mask_init_k<<<EW_G, 256, 0, stream>>>(sc, t1, maskb);

    // two suppression iterations
    for (int it = 0; it < 2; ++it) {
        maxpool5_k<<<mpG, mpB, 0, stream>>>(maskb, nullptr, t1);  // dilation
        maxpool5_k<<<mpG, mpB, 0, stream>>>(sc, t1, t2);          // maxpool(supp_scores)
        mask_update_k<<<EW_G, 256, 0, stream>>>(maskb, t1, sc, t2);
    }

    histo_k<<<EW_G, 256, 0, stream>>>(sc, maskb, hist);
    scan_k<<<BATCH, 256, 0, stream>>>(hist, bstar);
    compact_k<<<EW_G, 256, 0, stream>>>(sc, maskb, bstar, cnt, cand);
    finalize_k<<<BATCH, 1024, 0, stream>>>(sc, dm, cnt, cand, out);
}

// Round 2
// 978.655 us; speedup vs baseline: 1.2193x; 1.2193x over previous
//
#include <hip/hip_runtime.h>
#include <cstdint>

#define HH 480
#define WW 640
#define BATCH 8
#define NPIX (HH * WW)
#define TOPK 500
#define NBINS 4096
#define POOLCAP 32768
#define TS 32
#define HALO 10
#define LT 52  // TS + 2*HALO

// ---------------------------------------------------------------------------
// Fused 2-iteration modified NMS. Final mask at p depends on scores within
// radius 10, so a 32x32 tile + halo 10 reproduces the reference bit-exactly
// (max/compare only). Survivors (interior, border-clipped) are pushed to a
// per-batch candidate pool with block-aggregated atomics.
// ---------------------------------------------------------------------------
__global__ __launch_bounds__(256) void fused_nms_k(const float* __restrict__ sc,
                                                   unsigned* __restrict__ cnt,
                                                   unsigned long long* __restrict__ pool) {
    __shared__ float S[LT][LT + 1];
    __shared__ float T[LT][LT + 1];
    __shared__ float U[LT][LT + 1];
    __shared__ unsigned char M0[LT][LT];
    __shared__ unsigned char M1[LT][LT];
    __shared__ unsigned char SP[LT][LT];
    __shared__ unsigned long long lst[512];
    __shared__ unsigned lcnt, gbase;

    int bx = blockIdx.x * TS, by = blockIdx.y * TS, b = blockIdx.z;
    const float* img = sc + (size_t)b * NPIX;
    int lin = threadIdx.x;
    if (lin == 0) lcnt = 0;

    // A: load scores tile, -inf outside image (reduce_window pad semantics)
    for (int i = lin; i < LT * LT; i += 256) {
        int r = i / LT, c = i - r * LT;
        int gy = by + r - HALO, gx = bx + c - HALO;
        float v = -INFINITY;
        if (gy >= 0 && gy < HH && gx >= 0 && gx < WW) v = img[gy * WW + gx];
        S[r][c] = v;
    }
    __syncthreads();
    // B: rowmax(S) -> T, rows [0,52), cols [2,50)
    for (int i = lin; i < LT * 48; i += 256) {
        int r = i / 48, c = 2 + (i - r * 48);
        T[r][c] = fmaxf(fmaxf(fmaxf(S[r][c - 2], S[r][c - 1]),
                              fmaxf(S[r][c], S[r][c + 1])), S[r][c + 2]);
    }
    __syncthreads();
    // C: m0 = (s == maxpool(s)) at [2,50)^2 ; 0 outside image
    for (int i = lin; i < 48 * 48; i += 256) {
        int r = 2 + i / 48, c = 2 + i % 48;
        float m = fmaxf(fmaxf(fmaxf(T[r - 2][c], T[r - 1][c]),
                              fmaxf(T[r][c], T[r + 1][c])), T[r + 2][c]);
        int gy = by + r - HALO, gx = bx + c - HALO;
        bool inim = (gy >= 0 && gy < HH && gx >= 0 && gx < WW);
        M0[r][c] = (inim && S[r][c] == m) ? 1 : 0;
    }
    __syncthreads();
    // D: rowmax(M0) -> T, rows [2,50), cols [4,48)
    for (int i = lin; i < 48 * 44; i += 256) {
        int r = 2 + i / 44, c = 4 + i % 44;
        int mm = M0[r][c - 2] | M0[r][c - 1] | M0[r][c] | M0[r][c + 1] | M0[r][c + 2];
        T[r][c] = (float)mm;
    }
    __syncthreads();
    // E: supp1 at [4,48)^2 ; U = supp-scores (pad -inf outside image)
    for (int i = lin; i < 44 * 44; i += 256) {
        int r = 4 + i / 44, c = 4 + i % 44;
        float d = fmaxf(fmaxf(fmaxf(T[r - 2][c], T[r - 1][c]),
                              fmaxf(T[r][c], T[r + 1][c])), T[r + 2][c]);
        bool sp = d > 0.0f;
        SP[r][c] = sp ? 1 : 0;
        int gy = by + r - HALO, gx = bx + c - HALO;
        bool inim = (gy >= 0 && gy < HH && gx >= 0 && gx < WW);
        U[r][c] = inim ? (sp ? 0.0f : S[r][c]) : -INFINITY;
    }
    __syncthreads();
    // F: rowmax(U) -> T, rows [4,48), cols [6,46)
    for (int i = lin; i < 44 * 40; i += 256) {
        int r = 4 + i / 40, c = 6 + i % 40;
        T[r][c] = fmaxf(fmaxf(fmaxf(U[r][c - 2], U[r][c - 1]),
                              fmaxf(U[r][c], U[r][c + 1])), U[r][c + 2]);
    }
    __syncthreads();
    // G: m1 = m0 | (new_max & ~supp1) at [6,46)^2
    for (int i = lin; i < 40 * 40; i += 256) {
        int r = 6 + i / 40, c = 6 + i % 40;
        float m = fmaxf(fmaxf(fmaxf(T[r - 2][c], T[r - 1][c]),
                              fmaxf(T[r][c], T[r + 1][c])), T[r + 2][c]);
        int gy = by + r - HALO, gx = bx + c - HALO;
        bool inim = (gy >= 0 && gy < HH && gx >= 0 && gx < WW);
        bool nm = inim && !SP[r][c] && (U[r][c] == m);
        M1[r][c] = (M0[r][c] | (nm ? 1 : 0));
    }
    __syncthreads();
    // H: rowmax(M1) -> T, rows [6,46), cols [8,44)
    for (int i = lin; i < 40 * 36; i += 256) {
        int r = 6 + i / 36, c = 8 + i % 36;
        int mm = M1[r][c - 2] | M1[r][c - 1] | M1[r][c] | M1[r][c + 1] | M1[r][c + 2];
        T[r][c] = (float)mm;
    }
    __syncthreads();
    // I: supp2 at [8,44)^2 ; U = supp-scores round 2
    for (int i = lin; i < 36 * 36; i += 256) {
        int r = 8 + i / 36, c = 8 + i % 36;
        float d = fmaxf(fmaxf(fmaxf(T[r - 2][c], T[r - 1][c]),
                              fmaxf(T[r][c], T[r + 1][c])), T[r + 2][c]);
        bool sp = d > 0.0f;
        SP[r][c] = sp ? 1 : 0;
        int gy = by + r - HALO, gx = bx + c - HALO;
        bool inim = (gy >= 0 && gy < HH && gx >= 0 && gx < WW);
        U[r][c] = inim ? (sp ? 0.0f : S[r][c]) : -INFINITY;
    }
    __syncthreads();
    // J: rowmax(U) -> T, rows [8,44), cols [10,42)
    for (int i = lin; i < 36 * 32; i += 256) {
        int r = 8 + i / 32, c = 10 + (i & 31);
        T[r][c] = fmaxf(fmaxf(fmaxf(U[r][c - 2], U[r][c - 1]),
                              fmaxf(U[r][c], U[r][c + 1])), U[r][c + 2]);
    }
    __syncthreads();
    // K: final mask on interior [10,42)^2, push survivors
    for (int i = lin; i < 32 * 32; i += 256) {
        int r = 10 + (i >> 5), c = 10 + (i & 31);
        float m = fmaxf(fmaxf(fmaxf(T[r - 2][c], T[r - 1][c]),
                              fmaxf(T[r][c], T[r + 1][c])), T[r + 2][c]);
        bool nm = !SP[r][c] && (U[r][c] == m);
        bool m2 = M1[r][c] || nm;
        int gy = by + r - HALO, gx = bx + c - HALO;  // always in-image (tiles exact)
        if (m2 && gy >= 3 && gy <= HH - 3 && gx >= 3 && gx <= WW - 3) {
            unsigned pos = atomicAdd(&lcnt, 1u);
            if (pos < 512) {
                unsigned p = (unsigned)(gy * WW + gx);
                lst[pos] = ((unsigned long long)__float_as_uint(S[r][c]) << 32) |
                           (unsigned long long)(0xFFFFFFFFu - p);
            }
        }
    }
    __syncthreads();
    unsigned nl = lcnt < 512u ? lcnt : 512u;
    if (lin == 0 && nl) gbase = atomicAdd(&cnt[b], nl);
    __syncthreads();
    for (unsigned i = lin; i < nl; i += 256) {
        unsigned dst = gbase + i;
        if (dst < POOLCAP) pool[(size_t)b * POOLCAP + dst] = lst[i];
    }
}

__device__ __forceinline__ int bucket_of(float v) {
    int bk = (int)(v * 4096.0f);  // exact monotone for v in [0,1)
    return bk > 4095 ? 4095 : (bk < 0 ? 0 : bk);
}

__device__ __forceinline__ unsigned long long shfl_xor_u64(unsigned long long v, int m) {
    int lo = __shfl_xor((int)(unsigned)(v & 0xFFFFFFFFull), m, 64);
    int hi = __shfl_xor((int)(unsigned)(v >> 32), m, 64);
    return ((unsigned long long)(unsigned)hi << 32) | (unsigned long long)(unsigned)lo;
}

// Per-batch: histogram candidates -> exact top-500 threshold bucket -> filter
// -> bitonic sort 1024 (desc, index-ascending tie-break) -> softmax refine +
// kptscore + disp -> wave-per-keypoint descriptor sampling + L2 norm.
__global__ __launch_bounds__(1024) void finalize_k(const float* __restrict__ sc,
                                                   const float* __restrict__ dm,
                                                   const unsigned* __restrict__ cnt,
                                                   const unsigned long long* __restrict__ pool,
                                                   float* __restrict__ out) {
    int b = blockIdx.x;
    int tid = threadIdx.x;
    __shared__ unsigned hist[NBINS];
    __shared__ unsigned long long skeys[1024];
    __shared__ float spx[TOPK], spy[TOPK];
    __shared__ int bstar;
    __shared__ unsigned fcnt;

    for (int i = tid; i < NBINS; i += 1024) hist[i] = 0;
    if (tid == 0) fcnt = 0;
    __syncthreads();

    unsigned n = cnt[b];
    if (n > POOLCAP) n = POOLCAP;
    const unsigned long long* pb = pool + (size_t)b * POOLCAP;
    for (unsigned i = tid; i < n; i += 1024) {
        float v = __uint_as_float((unsigned)(pb[i] >> 32));
        atomicAdd(&hist[bucket_of(v)], 1u);
    }
    __syncthreads();
    if (tid == 0) {
        unsigned cum = 0;
        int B = 0;
        for (int bin = NBINS - 1; bin >= 0; --bin) {
            cum += hist[bin];
            if (cum >= TOPK) { B = bin; break; }
        }
        bstar = B;
    }
    __syncthreads();
    int Bs = bstar;
    for (unsigned i = tid; i < n; i += 1024) {
        unsigned long long k = pb[i];
        float v = __uint_as_float((unsigned)(k >> 32));
        if (bucket_of(v) >= Bs) {
            unsigned p = atomicAdd(&fcnt, 1u);
            if (p < 1024) skeys[p] = k;
        }
    }
    __syncthreads();
    unsigned nf = fcnt < 1024u ? fcnt : 1024u;
    unsigned long long key = (tid < (int)nf) ? skeys[tid] : 0ULL;

    // bitonic sort 1024, overall descending
    for (unsigned kk = 2; kk <= 1024; kk <<= 1) {
        for (unsigned j = kk >> 1; j > 0; j >>= 1) {
            unsigned long long partner;
            if (j >= 64) {
                __syncthreads();
                skeys[tid] = key;
                __syncthreads();
                partner = skeys[tid ^ j];
            } else {
                partner = shfl_xor_u64(key, (int)j);
            }
            bool keepMax = (((tid & kk) == 0) == ((tid & j) == 0));
            unsigned long long mx = key > partner ? key : partner;
            unsigned long long mn = key > partner ? partner : key;
            key = keepMax ? mx : mn;
        }
    }
    __syncthreads();

    // phase 1: per-keypoint softmax refinement
    if (tid < TOPK) {
        unsigned lo = (unsigned)(key & 0xFFFFFFFFull);
        int pix = (key == 0ULL) ? 0 : (int)(0xFFFFFFFFu - lo);
        int ys = pix / WW, xs = pix - ys * WW;
        const float* sp = sc + (size_t)b * NPIX;

        float p[25];
        float mxv = -INFINITY;
#pragma unroll
        for (int dy = 0; dy < 5; ++dy) {
            int iy = ys + dy - 2;
            iy = iy < 0 ? 0 : (iy > HH - 1 ? HH - 1 : iy);
#pragma unroll
            for (int dx = 0; dx < 5; ++dx) {
                int ix = xs + dx - 2;
                ix = ix < 0 ? 0 : (ix > WW - 1 ? WW - 1 : ix);
                float v = sp[iy * WW + ix];
                p[dy * 5 + dx] = v;
                mxv = fmaxf(mxv, v);
            }
        }
        float se = 0.f, sx = 0.f, sy = 0.f;
#pragma unroll
        for (int i = 0; i < 25; ++i) {
            float e = expf((p[i] - mxv) * 10.0f);
            p[i] = e;
            se += e;
            sx += e * (float)((i % 5) - 2);
            sy += e * (float)((i / 5) - 2);
        }
        float invs = 1.0f / (se + 1e-12f);
        float xr = sx * invs, yr = sy * invs;
        float dnum = 0.f;
#pragma unroll
        for (int i = 0; i < 25; ++i) {
            float ddx = ((float)((i % 5) - 2) - xr) * 0.5f;
            float ddy = ((float)((i / 5) - 2) - yr) * 0.5f;
            dnum += p[i] * (ddx * ddx + ddy * ddy);
        }
        float disp = dnum * invs;

        float kxn = ((float)xs + xr) / 639.0f * 2.0f - 1.0f;
        float kyn = ((float)ys + yr) / 479.0f * 2.0f - 1.0f;
        out[((size_t)b * TOPK + tid) * 2 + 0] = kxn;
        out[((size_t)b * TOPK + tid) * 2 + 1] = kyn;

        float px = fminf(fmaxf((kxn + 1.0f) * 0.5f * 639.0f, 0.0f), 639.0f);
        float py = fminf(fmaxf((kyn + 1.0f) * 0.5f * 479.0f, 0.0f), 479.0f);
        int x0 = (int)floorf(px), y0 = (int)floorf(py);
        int x1 = x0 + 1 > WW - 1 ? WW - 1 : x0 + 1;
        int y1 = y0 + 1 > HH - 1 ? HH - 1 : y0 + 1;
        float wx = px - (float)x0, wy = py - (float)y0;
        float v00 = sp[y0 * WW + x0], v01 = sp[y0 * WW + x1];
        float v10 = sp[y1 * WW + x0], v11 = sp[y1 * WW + x1];
        float ks = v00 * (1 - wx) * (1 - wy) + v01 * wx * (1 - wy) +
                   v10 * (1 - wx) * wy + v11 * wx * wy;
        out[264000 + b * TOPK + tid] = ks;
        out[268000 + b * TOPK + tid] = disp;
        spx[tid] = px;
        spy[tid] = py;
    }
    __syncthreads();

    // phase 2: descriptor sampling; wave per keypoint, lane = channel
    int wave = tid >> 6, lane = tid & 63;
    for (int kp = wave; kp < TOPK; kp += 16) {
        float px = spx[kp], py = spy[kp];
        int x0 = (int)floorf(px), y0 = (int)floorf(py);
        int x1 = x0 + 1 > WW - 1 ? WW - 1 : x0 + 1;
        int y1 = y0 + 1 > HH - 1 ? HH - 1 : y0 + 1;
        float wx = px - (float)x0, wy = py - (float)y0;
        const float* ch = dm + ((size_t)b * 64 + lane) * NPIX;
        float v00 = ch[y0 * WW + x0], v01 = ch[y0 * WW + x1];
        float v10 = ch[y1 * WW + x0], v11 = ch[y1 * WW + x1];
        float d = v00 * (1 - wx) * (1 - wy) + v01 * wx * (1 - wy) +
                  v10 * (1 - wx) * wy + v11 * wx * wy;
        float ssq = d * d;
#pragma unroll
        for (int m = 32; m; m >>= 1) ssq += __shfl_xor(ssq, m, 64);
        float inv = 1.0f / fmaxf(sqrtf(ssq), 1e-12f);
        out[8000 + ((size_t)b * TOPK + kp) * 64 + lane] = d * inv;
    }
}

extern "C" void kernel_launch(void* const* d_in, const int* in_sizes, int n_in,
                              void* d_out, int out_size, void* d_ws, size_t ws_size,
                              hipStream_t stream) {
    const float* sc = (const float*)d_in[0];
    const float* dm = (const float*)d_in[1];
    float* out = (float*)d_out;

    char* ws = (char*)d_ws;
    unsigned* cnt = (unsigned*)ws;                          // 8 u32
    unsigned long long* pool = (unsigned long long*)(ws + 64);  // 8 * POOLCAP u64

    hipMemsetAsync(cnt, 0, BATCH * sizeof(unsigned), stream);

    dim3 g1(WW / TS, HH / TS, BATCH);
    fused_nms_k<<<g1, 256, 0, stream>>>(sc, cnt, pool);
    finalize_k<<<BATCH, 1024, 0, stream>>>(sc, dm, cnt, pool, out);
}